// Round 5
// baseline (590.495 us; speedup 1.0000x reference)
//
#include <hip/hip_runtime.h>

// Problem constants
#define D_DIM 1024
#define L_DIM 4096
#define B_DIM 4
#define M_DIM (B_DIM * L_DIM)   // 16384 rows
#define N1    3072              // concat of K1|Q1|K2 outputs
#define KDIM  1024
#define NKT   16                // K tiles of 64

using f32x4  = __attribute__((ext_vector_type(4))) float;
using bf16x8 = __attribute__((ext_vector_type(8))) short;

__device__ __forceinline__ unsigned short f2bf(float f) {
    unsigned u = __float_as_uint(f);
    u += 0x7fffu + ((u >> 16) & 1u);   // RNE
    return (unsigned short)(u >> 16);
}
__device__ __forceinline__ float bf2f(unsigned short h) {
    return __uint_as_float(((unsigned)h) << 16);
}
__device__ __forceinline__ float sigmoidf_(float x) {
    return 1.0f / (1.0f + __expf(-x));
}

// fp32 -> bf16 conversion, 4 elems/thread
__global__ void cvt_bf16_kernel(const float* __restrict__ in, unsigned short* __restrict__ out, int n) {
    int i = (blockIdx.x * blockDim.x + threadIdx.x) * 4;
    if (i < n) {
        float4 v = *reinterpret_cast<const float4*>(in + i);
        uint2 p;
        p.x = (unsigned)f2bf(v.x) | ((unsigned)f2bf(v.y) << 16);
        p.y = (unsigned)f2bf(v.z) | ((unsigned)f2bf(v.w) << 16);
        *reinterpret_cast<uint2*>(out + i) = p;
    }
}

__device__ __forceinline__ void gld_lds16(const void* g, void* s) {
    __builtin_amdgcn_global_load_lds((const __attribute__((address_space(1))) void*)g,
                                     (__attribute__((address_space(3))) void*)s, 16, 0, 0);
}

#define BAR()  do { asm volatile("" ::: "memory"); __builtin_amdgcn_s_barrier(); asm volatile("" ::: "memory"); } while (0)
#define MFMA16(a_, b_, c_) __builtin_amdgcn_mfma_f32_16x16x32_bf16(a_, b_, c_, 0, 0, 0)

// ============================================================================
// 256x256 tile, BK=64, 8 waves (2M x 4N), 512 threads, 128 KiB LDS dbuf.
// (unchanged from round 3 — 731 TF on GEMM1)
// ============================================================================
__global__ __launch_bounds__(512, 2) void gemm256(
        const unsigned short* __restrict__ A, const unsigned short* __restrict__ Bm,
        unsigned short* __restrict__ Cb, float* __restrict__ Cf,
        const float* __restrict__ bb0, const float* __restrict__ bb1, const float* __restrict__ bb2,
        int nwgDiv8, int mode) {
    extern __shared__ __align__(16) short lds[];
    const int tid  = threadIdx.x;
    const int wid  = tid >> 6, lane = tid & 63;
    const int wr   = wid >> 2, wc = wid & 3;      // 2M x 4N waves
    const int lr   = lane & 15, kg = lane >> 4;

    int lin = blockIdx.y * 64 + blockIdx.x;
    int swz = (lin & 7) * nwgDiv8 + (lin >> 3);
    int bm = swz & 63;
    int bn = swz >> 6;
    const size_t rowA0 = (size_t)bm * 256;
    const size_t rowB0 = (size_t)bn * 256;

    const int rh = tid >> 2;
    const int sl = (tid & 3) ^ ((rh >> 1) & 3);
    const int wbase = (tid >> 6) * 512;
    const size_t aoffG = (size_t)rh * KDIM + sl * 8;

#define STAGE(Mp_, row0_, kt_, kh_, c_, mat_, cur_) \
    gld_lds16((Mp_) + ((row0_) + (size_t)(c_) * 128) * KDIM + (size_t)(kt_) * 64 + (kh_) * 32 + aoffG, \
              (void*)(lds + (cur_) * 32768 + (mat_) * 16384 + (kh_) * 8192 + (c_) * 4096 + wbase))

    const int slotR = kg ^ ((lr >> 1) & 3);
    const int aRd = (wr * 128 + lr) * 32 + slotR * 8;
    const int bRd = (wc * 64  + lr) * 32 + slotR * 8;

    f32x4 acc[8][4];
#pragma unroll
    for (int i = 0; i < 8; ++i)
#pragma unroll
        for (int j = 0; j < 4; ++j) acc[i][j] = (f32x4){0.f, 0.f, 0.f, 0.f};

    STAGE(A,  rowA0, 0, 0, 0, 0, 0); STAGE(A,  rowA0, 0, 0, 1, 0, 0);
    STAGE(Bm, rowB0, 0, 0, 0, 1, 0); STAGE(Bm, rowB0, 0, 0, 1, 1, 0);
    STAGE(A,  rowA0, 0, 1, 0, 0, 0); STAGE(A,  rowA0, 0, 1, 1, 0, 0);
    STAGE(Bm, rowB0, 0, 1, 0, 1, 0); STAGE(Bm, rowB0, 0, 1, 1, 1, 0);
    STAGE(A,  rowA0, 1, 0, 0, 0, 1); STAGE(A,  rowA0, 1, 0, 1, 0, 1);
    STAGE(Bm, rowB0, 1, 0, 0, 1, 1); STAGE(Bm, rowB0, 1, 0, 1, 1, 1);
    asm volatile("s_waitcnt vmcnt(4)" ::: "memory");
    BAR();

    for (int kt = 0; kt < NKT; ++kt) {
        const int cur = kt & 1;
        const short* A0 = lds + cur * 32768;
        const short* A1 = A0 + 8192;
        const short* B0 = A0 + 16384;
        const short* B1 = A0 + 24576;
        bf16x8 a[8], b0, b1, b2, b3;

        #pragma unroll
        for (int fm = 0; fm < 8; ++fm) a[fm] = *reinterpret_cast<const bf16x8*>(A0 + aRd + fm * 512);
        b0 = *reinterpret_cast<const bf16x8*>(B0 + bRd);
        b1 = *reinterpret_cast<const bf16x8*>(B0 + bRd + 512);
        b2 = *reinterpret_cast<const bf16x8*>(B0 + bRd + 1024);
        b3 = *reinterpret_cast<const bf16x8*>(B0 + bRd + 1536);
        if (kt + 1 < NKT) {
            const int nc = cur ^ 1;
            STAGE(A,  rowA0, kt + 1, 1, 0, 0, nc); STAGE(A,  rowA0, kt + 1, 1, 1, 0, nc);
            STAGE(Bm, rowB0, kt + 1, 1, 0, 1, nc); STAGE(Bm, rowB0, kt + 1, 1, 1, 1, nc);
        }
        BAR();
        __builtin_amdgcn_s_setprio(1);
        #pragma unroll
        for (int fm = 0; fm < 8; ++fm) {
            acc[fm][0] = MFMA16(b0, a[fm], acc[fm][0]);
            acc[fm][1] = MFMA16(b1, a[fm], acc[fm][1]);
        }
        __builtin_amdgcn_s_setprio(0);
        BAR();

        BAR();
        __builtin_amdgcn_s_setprio(1);
        #pragma unroll
        for (int fm = 0; fm < 8; ++fm) {
            acc[fm][2] = MFMA16(b2, a[fm], acc[fm][2]);
            acc[fm][3] = MFMA16(b3, a[fm], acc[fm][3]);
        }
        __builtin_amdgcn_s_setprio(0);
        BAR();

        #pragma unroll
        for (int fm = 0; fm < 8; ++fm) a[fm] = *reinterpret_cast<const bf16x8*>(A1 + aRd + fm * 512);
        b0 = *reinterpret_cast<const bf16x8*>(B1 + bRd);
        b1 = *reinterpret_cast<const bf16x8*>(B1 + bRd + 512);
        b2 = *reinterpret_cast<const bf16x8*>(B1 + bRd + 1024);
        b3 = *reinterpret_cast<const bf16x8*>(B1 + bRd + 1536);
        if (kt + 2 < NKT) {
            STAGE(A, rowA0, kt + 2, 0, 0, 0, cur); STAGE(A, rowA0, kt + 2, 0, 1, 0, cur);
        }
        BAR();
        __builtin_amdgcn_s_setprio(1);
        #pragma unroll
        for (int fm = 0; fm < 8; ++fm) {
            acc[fm][0] = MFMA16(b0, a[fm], acc[fm][0]);
            acc[fm][1] = MFMA16(b1, a[fm], acc[fm][1]);
        }
        __builtin_amdgcn_s_setprio(0);
        BAR();

        if (kt + 2 < NKT) {
            STAGE(Bm, rowB0, kt + 2, 0, 0, 1, cur); STAGE(Bm, rowB0, kt + 2, 0, 1, 1, cur);
        }
        BAR();
        __builtin_amdgcn_s_setprio(1);
        #pragma unroll
        for (int fm = 0; fm < 8; ++fm) {
            acc[fm][2] = MFMA16(b2, a[fm], acc[fm][2]);
            acc[fm][3] = MFMA16(b3, a[fm], acc[fm][3]);
        }
        __builtin_amdgcn_s_setprio(0);
        if (kt < NKT - 2) { asm volatile("s_waitcnt vmcnt(4)" ::: "memory"); }
        else              { asm volatile("s_waitcnt vmcnt(0)" ::: "memory"); }
        BAR();
    }

    const int rowBase = bm * 256 + wr * 128;
    const int colBase = bn * 256 + wc * 64;
    if (mode == 0) {
        const int seg = (colBase >> 10);
        const float* bs = (seg == 0) ? bb0 : ((seg == 1) ? bb1 : bb2);
#pragma unroll
        for (int fm = 0; fm < 8; ++fm) {
            int row = rowBase + fm * 16 + lr;
            unsigned short* cp = Cb + (size_t)row * 3072;
#pragma unroll
            for (int fn = 0; fn < 4; ++fn) {
                int col0 = colBase + fn * 16 + kg * 4;
                float4 b4 = *reinterpret_cast<const float4*>(bs + (col0 & 1023));
                float v0 = acc[fm][fn][0] + b4.x;
                float v1 = acc[fm][fn][1] + b4.y;
                float v2 = acc[fm][fn][2] + b4.z;
                float v3 = acc[fm][fn][3] + b4.w;
                float r0, r1, r2, r3;
                if (seg == 0)      { r0 = __expf(v0); r1 = __expf(v1); r2 = __expf(v2); r3 = __expf(v3); }
                else if (seg == 1) { r0 = sigmoidf_(v0); r1 = sigmoidf_(v1); r2 = sigmoidf_(v2); r3 = sigmoidf_(v3); }
                else               { r0 = sigmoidf_(v0 * 6.25e-4f); r1 = sigmoidf_(v1 * 6.25e-4f);
                                     r2 = sigmoidf_(v2 * 6.25e-4f); r3 = sigmoidf_(v3 * 6.25e-4f); }
                uint2 p;
                p.x = (unsigned)f2bf(r0) | ((unsigned)f2bf(r1) << 16);
                p.y = (unsigned)f2bf(r2) | ((unsigned)f2bf(r3) << 16);
                *reinterpret_cast<uint2*>(cp + col0) = p;
            }
        }
    } else {
#pragma unroll
        for (int fm = 0; fm < 8; ++fm) {
            int row = rowBase + fm * 16 + lr;
            float* cp = Cf + (size_t)row * 1024;
#pragma unroll
            for (int fn = 0; fn < 4; ++fn) {
                int col0 = colBase + fn * 16 + kg * 4;
                float4 b4 = *reinterpret_cast<const float4*>(bb0 + col0);
                float4 v;
                v.x = acc[fm][fn][0] + b4.x;
                v.y = acc[fm][fn][1] + b4.y;
                v.z = acc[fm][fn][2] + b4.z;
                v.w = acc[fm][fn][3] + b4.w;
                *reinterpret_cast<float4*>(cp + col0) = v;
            }
        }
    }
#undef STAGE
}

// ============================================================================
// Fused scan: pass1 + chunk-scan + pass3 + chunk-scan + pass5 in ONE kernel.
// 1024 virtual tiles (b:4, dq:4, c:64); ticket-ordered (deadlock-free under
// undefined dispatch order); decoupled lookback via 8-byte marker|f32 atomic
// words (AGENT scope -> cross-XCD coherent); lookback sum in fixed ascending
// order -> bitwise deterministic. oar/m stay in LDS (each thread reads only
// its own writes -> no barriers needed).
// ============================================================================
#define MARKV 0x5A5A5A5Au

__device__ __forceinline__ void publish(unsigned long long* p, float v) {
    unsigned long long w = ((unsigned long long)MARKV << 32) | (unsigned long long)__float_as_uint(v);
    __hip_atomic_store(p, w, __ATOMIC_RELEASE, __HIP_MEMORY_SCOPE_AGENT);
}
__device__ __forceinline__ float waitval(unsigned long long* p) {
    unsigned long long w = __hip_atomic_load(p, __ATOMIC_RELAXED, __HIP_MEMORY_SCOPE_AGENT);
    while ((unsigned)(w >> 32) != MARKV) {
        __builtin_amdgcn_s_sleep(4);
        w = __hip_atomic_load(p, __ATOMIC_RELAXED, __HIP_MEMORY_SCOPE_AGENT);
    }
    return __uint_as_float((unsigned)w);
}

__global__ __launch_bounds__(256) void fused_scan(
        const unsigned short* __restrict__ KQ, const unsigned short* __restrict__ xbf,
        unsigned short* __restrict__ yin, unsigned long long* parts, unsigned* ticket) {
    extern __shared__ unsigned short sm[];
    unsigned short* oarS = sm;            // [64][256]
    unsigned short* mS   = sm + 16384;    // [64][256]
    __shared__ unsigned vsh;

    const int thr = threadIdx.x;
    if (thr == 0)
        vsh = __hip_atomic_fetch_add(ticket, 1u, __ATOMIC_RELAXED, __HIP_MEMORY_SCOPE_AGENT);
    __syncthreads();
    const unsigned v = vsh;
    const int c = v & 63, grp = v >> 6;        // grp in [0,16)
    const int b = grp >> 2, dq = grp & 3;
    const int d = dq * 256 + thr;
    const size_t row0 = (size_t)b * L_DIM + (size_t)c * 64;
    const unsigned short* kqp = KQ + row0 * 3072 + d;   // k:+0  q:+1024  k2:+2048
    const unsigned short* vp  = xbf + row0 * 1024 + d;

    unsigned long long* pK  = parts;                     // [16][64][256]
    unsigned long long* pKV = parts + 16 * 64 * 256;
    unsigned long long* pM  = parts + 2 * 16 * 64 * 256;
    const size_t slot = ((size_t)grp * 64 + c) * 256 + thr;

    // ---- phase A: chunk partial sums of K, K*V
    float sK = 0.f, sKV = 0.f;
#pragma unroll 8
    for (int t = 0; t < 64; ++t) {
        float k = bf2f(kqp[(size_t)t * 3072]);
        float w = bf2f(vp[(size_t)t * 1024]);
        sK += k; sKV += k * w;
    }
    publish(&pK[slot], sK);
    publish(&pKV[slot], sKV);

    // lookback (ascending, deterministic)
    float offK = 0.f, offKV = 0.f;
    for (int cp = 0; cp < c; ++cp) {
        size_t s2 = ((size_t)grp * 64 + cp) * 256 + thr;
        offK  += waitval(&pK[s2]);
        offKV += waitval(&pKV[s2]);
    }

    // ---- phase B: oar + m, stash in LDS, chunk sum of m
    float cK = offK, cKV = offKV;
    float oar_prev = 0.f, k2_prev = 0.f;
    if (c != 0) {
        float qm1 = bf2f(kqp[-3072 + 1024]);
        oar_prev = qm1 * (cKV / (cK + 1e-6f));
        k2_prev  = bf2f(kqp[-3072 + 2048]);
    }
    float sM = 0.f;
#pragma unroll 4
    for (int t = 0; t < 64; ++t) {
        float k  = bf2f(kqp[(size_t)t * 3072]);
        float q  = bf2f(kqp[(size_t)t * 3072 + 1024]);
        float k2 = bf2f(kqp[(size_t)t * 3072 + 2048]);
        float w  = bf2f(vp[(size_t)t * 1024]);
        cK += k; cKV += k * w;
        float oar = q * (cKV / (cK + 1e-6f));
        float m = k2_prev * (w - oar_prev);    // t==0 && c==0: both 0 -> m=0
        sM += m;
        oarS[t * 256 + thr] = f2bf(oar);
        mS[t * 256 + thr]   = f2bf(m);
        oar_prev = oar; k2_prev = k2;
    }
    publish(&pM[slot], sM);

    float offM = 0.f;
    for (int cp = 0; cp < c; ++cp) {
        size_t s2 = ((size_t)grp * 64 + cp) * 256 + thr;
        offM += waitval(&pM[s2]);
    }

    // ---- phase C: yin = oar + cumsum(m)*6.25e-4*Q[t-1]
    float cM = offM;
    {
        cM += bf2f(mS[thr]);
        float qm1 = (c == 0) ? 0.f : bf2f(kqp[-3072 + 1024]);
        yin[row0 * 1024 + d] = f2bf(bf2f(oarS[thr]) + cM * 6.25e-4f * qm1);
    }
#pragma unroll 4
    for (int t = 1; t < 64; ++t) {
        cM += bf2f(mS[t * 256 + thr]);
        float qm1 = bf2f(kqp[(size_t)(t - 1) * 3072 + 1024]);
        yin[(row0 + (size_t)t) * 1024 + d] = f2bf(bf2f(oarS[t * 256 + thr]) + cM * 6.25e-4f * qm1);
    }
}

extern "C" void kernel_launch(void* const* d_in, const int* in_sizes, int n_in,
                              void* d_out, int out_size, void* d_ws, size_t ws_size,
                              hipStream_t stream) {
    (void)in_sizes; (void)n_in; (void)out_size; (void)ws_size;
    const float* x   = (const float*)d_in[0];
    const float* Wq1 = (const float*)d_in[1];
    const float* bq1 = (const float*)d_in[2];
    const float* Wk1 = (const float*)d_in[3];
    const float* bk1 = (const float*)d_in[4];
    const float* Wk2 = (const float*)d_in[5];
    const float* bk2 = (const float*)d_in[6];
    const float* Wpj = (const float*)d_in[7];
    const float* bpj = (const float*)d_in[8];
    float* out = (float*)d_out;

    char* ws = (char*)d_ws;
    unsigned short* xbf   = (unsigned short*)(ws);                  // 33,554,432 B
    unsigned short* Wcat  = (unsigned short*)(ws + 33554432);       //  6,291,456 B
    unsigned short* Wpjbf = (unsigned short*)(ws + 39845888);       //  2,097,152 B
    unsigned short* KQ    = (unsigned short*)(ws + 41943040);       // 100,663,296 B
    unsigned short* yin   = (unsigned short*)(ws + 142606336);      // 33,554,432 B
    unsigned long long* parts = (unsigned long long*)(ws + 176160768); // 6,291,456 B (3 x 16*64*256 u64)
    unsigned* ticket = (unsigned*)(ws + 182452224);                 // 4 B
    // total ~174 MiB

    (void)hipFuncSetAttribute((const void*)gemm256,
                              hipFuncAttributeMaxDynamicSharedMemorySize, 131072);
    (void)hipFuncSetAttribute((const void*)fused_scan,
                              hipFuncAttributeMaxDynamicSharedMemorySize, 65536);

    // reset lookback state (parts + ticket) every call -> deterministic replays
    (void)hipMemsetAsync(parts, 0, 6291456 + 64, stream);

    const int nx = M_DIM * D_DIM;
    const int nw = D_DIM * D_DIM;
    cvt_bf16_kernel<<<nx / 4 / 256, 256, 0, stream>>>(x, xbf, nx);
    cvt_bf16_kernel<<<nw / 4 / 256, 256, 0, stream>>>(Wk1, Wcat, nw);
    cvt_bf16_kernel<<<nw / 4 / 256, 256, 0, stream>>>(Wq1, Wcat + nw, nw);
    cvt_bf16_kernel<<<nw / 4 / 256, 256, 0, stream>>>(Wk2, Wcat + 2 * nw, nw);
    cvt_bf16_kernel<<<nw / 4 / 256, 256, 0, stream>>>(Wpj, Wpjbf, nw);

    // GEMM1: 16384 x 3072 x 1024, bf16 out with activations
    gemm256<<<dim3(64, 12), 512, 131072, stream>>>(xbf, Wcat, KQ, nullptr,
                                                   bk1, bq1, bk2, 96, 0);

    // fused scan chain (replaces pass1/scan_ex2/pass3/scan_ex1/pass5)
    fused_scan<<<1024, 256, 65536, stream>>>(KQ, xbf, yin, parts, ticket);

    // GEMM2: 16384 x 1024 x 1024, fp32 out with bias
    gemm256<<<dim3(64, 4), 512, 131072, stream>>>(yin, Wpjbf, nullptr, out,
                                                  bpj, nullptr, nullptr, 32, 1);
}